// Round 2
// baseline (1424.581 us; speedup 1.0000x reference)
//
#include <hip/hip_runtime.h>

#define BB 256
#define LL 1024
#define TT 128

// Static (small) shared state; bp table is either dynamic LDS (128 KB) or global ws.
struct SmallSmem {
    float state[TT];          // 512 B, float4-aligned (first member)
    float pv[256];            // partial best values
    int   pi[256];            // partial best indices (local 0..63)
    unsigned char tags[LL];   // decoded tags staging
};

template <bool BP_IN_LDS>
__global__ __launch_bounds__(256)
void viterbi_kernel(const float* __restrict__ x,
                    const int* __restrict__ lengths,
                    const float* __restrict__ trans,
                    int* __restrict__ out,
                    unsigned char* __restrict__ bp_ws) {
    __shared__ SmallSmem sm;
    extern __shared__ unsigned char bp_lds[];   // L*T bytes when BP_IN_LDS

    const int b   = blockIdx.x;
    const int tid = threadIdx.x;
    const int j   = tid & (TT - 1);   // tag column 0..127
    const int h   = tid >> 7;         // predecessor half: 0 -> i in [0,64), 1 -> [64,128)

    unsigned char* bp = BP_IN_LDS ? bp_lds : (bp_ws + (size_t)b * LL * TT);

    int lenb = lengths[b];
    if (lenb < 1) lenb = 1;
    if (lenb > LL) lenb = LL;

    // Register-cache this thread's trans column-half: tc[ii] = trans[h*64+ii][j]
    float tc[64];
    #pragma unroll
    for (int ii = 0; ii < 64; ++ii)
        tc[ii] = trans[(h * 64 + ii) * TT + j];

    const float* xb = x + (size_t)b * LL * TT;

    if (tid < TT) sm.state[tid] = xb[tid];
    __syncthreads();

    // ---------------- forward ----------------
    for (int t = 1; t < lenb; ++t) {
        // emission for this step (only needed at merge; issue load early)
        float xv = (tid < TT) ? xb[t * TT + j] : 0.0f;

        // scan 64 predecessors: score = state[i] + trans[i][j]
        // Accumulator r tracks indices i = 4q+r, q ascending; strict > keeps the
        // LOWEST index within each residue class (jnp.argmax = first max).
        float best0 = -3.4e38f, best1 = -3.4e38f, best2 = -3.4e38f, best3 = -3.4e38f;
        int   bi0 = 0, bi1 = 1, bi2 = 2, bi3 = 3;
        const float4* st4 = reinterpret_cast<const float4*>(sm.state + h * 64);
        #pragma unroll
        for (int q = 0; q < 16; ++q) {
            float4 sv = st4[q];            // wave-uniform broadcast ds_read_b128
            float s0 = sv.x + tc[4 * q + 0];
            float s1 = sv.y + tc[4 * q + 1];
            float s2 = sv.z + tc[4 * q + 2];
            float s3 = sv.w + tc[4 * q + 3];
            if (s0 > best0) { best0 = s0; bi0 = 4 * q + 0; }
            if (s1 > best1) { best1 = s1; bi1 = 4 * q + 1; }
            if (s2 > best2) { best2 = s2; bi2 = 4 * q + 2; }
            if (s3 > best3) { best3 = s3; bi3 = 4 * q + 3; }
        }
        // Merge accumulators with EXACT first-index tie-break:
        // take candidate iff value strictly greater, or equal with smaller index.
        float bb = best0; int bi = bi0;
        if (best1 > bb || (best1 == bb && bi1 < bi)) { bb = best1; bi = bi1; }
        if (best2 > bb || (best2 == bb && bi2 < bi)) { bb = best2; bi = bi2; }
        if (best3 > bb || (best3 == bb && bi3 < bi)) { bb = best3; bi = bi3; }
        sm.pv[tid] = bb;
        sm.pi[tid] = bi;
        __syncthreads();

        if (tid < TT) {
            float b0 = sm.pv[tid];
            float b1 = sm.pv[tid + 128];
            int   i0 = sm.pi[tid];             // global i in [0,64)
            int   i1 = sm.pi[tid + 128] + 64;  // global i in [64,128)
            // All half-0 indices < all half-1 indices, so strict > (half-0 wins
            // ties) is exactly first-index semantics.
            float bv = b0; int ix = i0;
            if (b1 > bv) { bv = b1; ix = i1; }
            sm.state[j]  = bv + xv;
            bp[t * TT + j] = (unsigned char)ix;
        }
        __syncthreads();
    }

    // ---------------- backward ----------------
    if (tid == 0) {
        // last_tag = argmax(state), first-index tiebreak (sequential strict >)
        float bv = sm.state[0]; int ix = 0;
        for (int i = 1; i < TT; ++i) {
            float v = sm.state[i];
            if (v > bv) { bv = v; ix = i; }
        }
        int carry = ix;
        for (int t = lenb - 1; t >= 1; --t) {
            sm.tags[t] = (unsigned char)carry;
            carry = bp[t * TT + carry];
        }
        sm.tags[0] = (unsigned char)carry;
    }
    __syncthreads();

    int* outb = out + (size_t)b * LL;
    for (int t = tid; t < LL; t += 256)
        outb[t] = (t < lenb) ? (int)sm.tags[t] : 0;
}

extern "C" void kernel_launch(void* const* d_in, const int* in_sizes, int n_in,
                              void* d_out, int out_size, void* d_ws, size_t ws_size,
                              hipStream_t stream) {
    const float* x       = (const float*)d_in[0];
    const int*   lengths = (const int*)d_in[1];
    // d_in[2] = tags (unused by decode)
    const float* trans   = (const float*)d_in[3];
    int*         out     = (int*)d_out;

    const size_t bp_bytes = (size_t)BB * LL * TT;  // 33.5 MB
    if (ws_size >= bp_bytes) {
        // Safe path: backpointers in global workspace.
        viterbi_kernel<false><<<BB, 256, 0, stream>>>(x, lengths, trans, out,
                                                      (unsigned char*)d_ws);
    } else {
        // Fast path: backpointers entirely in LDS (128 KB dynamic + ~3.5 KB static).
        const int dyn = LL * TT;  // 131072 bytes
        hipFuncSetAttribute((const void*)&viterbi_kernel<true>,
                            hipFuncAttributeMaxDynamicSharedMemorySize, dyn);
        viterbi_kernel<true><<<BB, 256, dyn, stream>>>(x, lengths, trans, out, nullptr);
    }
}

// Round 3
// 934.684 us; speedup vs baseline: 1.5241x; 1.5241x over previous
//
#include <hip/hip_runtime.h>

#define BB 256
#define LL 1024
#define TT 128
#define NTH 512

// CK-style LDS-only barrier: does NOT drain vmcnt, so in-flight global
// prefetch loads stay outstanding across the barrier (unlike __syncthreads,
// which lowers to s_waitcnt vmcnt(0) lgkmcnt(0) + s_barrier).
__device__ __forceinline__ void lds_barrier() {
    asm volatile("s_waitcnt lgkmcnt(0)\n\ts_barrier" ::);
}

struct SmallSmem {
    float state[TT];          // current Viterbi state (float4-aligned, first)
    float pv[NTH];            // partial best values (per thread)
    int   pi[NTH];            // partial best GLOBAL indices
    unsigned char tags[LL];   // decoded tags staging
};

__global__ __launch_bounds__(NTH)
void viterbi_kernel(const float* __restrict__ x,
                    const int* __restrict__ lengths,
                    const float* __restrict__ trans,
                    int* __restrict__ out) {
    __shared__ SmallSmem sm;
    extern __shared__ unsigned char bp[];   // LL*TT bytes, backpointers in LDS

    const int b   = blockIdx.x;
    const int tid = threadIdx.x;
    const int j   = tid & (TT - 1);   // tag column 0..127
    const int q   = tid >> 7;         // predecessor quarter: i in [32q, 32q+32)

    int lenb = lengths[b];
    if (lenb < 1) lenb = 1;
    if (lenb > LL) lenb = LL;

    // Register-cache this thread's 32 trans values: tc[ii] = trans[32q+ii][j]
    float tc[32];
    #pragma unroll
    for (int ii = 0; ii < 32; ++ii)
        tc[ii] = trans[(q * 32 + ii) * TT + j];

    const float* xb = x + (size_t)b * LL * TT;

    if (tid < TT) sm.state[tid] = xb[tid];

    // Emission prefetch: xv_cur holds x[t][j] when iteration t runs.
    float xv_cur = 0.0f, xv_next = 0.0f;
    if (tid < TT && lenb > 1) xv_cur = xb[TT + j];
    lds_barrier();

    // ---------------- forward ----------------
    for (int t = 1; t < lenb; ++t) {
        // prefetch next step's emission (clamped; stays in flight across barriers)
        if (tid < TT) {
            int tn = (t + 1 < lenb) ? (t + 1) : (lenb - 1);
            xv_next = xb[tn * TT + j];
        }

        // scan 32 predecessors: score = state[i] + trans[i][j]
        // Residue accumulator r tracks local ii = 4k+r, k ascending; strict >
        // keeps the LOWEST index within each residue (jnp.argmax = first max).
        float best0 = -3.4e38f, best1 = -3.4e38f, best2 = -3.4e38f, best3 = -3.4e38f;
        int   bi0 = 0, bi1 = 1, bi2 = 2, bi3 = 3;
        const float4* st4 = reinterpret_cast<const float4*>(sm.state + q * 32);
        #pragma unroll
        for (int k = 0; k < 8; ++k) {
            float4 sv = st4[k];            // wave-uniform broadcast ds_read_b128
            float s0 = sv.x + tc[4 * k + 0];
            float s1 = sv.y + tc[4 * k + 1];
            float s2 = sv.z + tc[4 * k + 2];
            float s3 = sv.w + tc[4 * k + 3];
            if (s0 > best0) { best0 = s0; bi0 = 4 * k + 0; }
            if (s1 > best1) { best1 = s1; bi1 = 4 * k + 1; }
            if (s2 > best2) { best2 = s2; bi2 = 4 * k + 2; }
            if (s3 > best3) { best3 = s3; bi3 = 4 * k + 3; }
        }
        // merge residues with EXACT first-index tie-break
        float bb = best0; int bi = bi0;
        if (best1 > bb || (best1 == bb && bi1 < bi)) { bb = best1; bi = bi1; }
        if (best2 > bb || (best2 == bb && bi2 < bi)) { bb = best2; bi = bi2; }
        if (best3 > bb || (best3 == bb && bi3 < bi)) { bb = best3; bi = bi3; }
        sm.pv[tid] = bb;
        sm.pi[tid] = bi + q * 32;   // global predecessor index
        lds_barrier();

        if (tid < TT) {
            // Quarters in ascending order; all q0 indices < q1 < q2 < q3, so
            // strict > (earlier quarter wins ties) = first-index semantics.
            float bv = sm.pv[j];       int ix = sm.pi[j];
            float v1 = sm.pv[j + 128]; int i1 = sm.pi[j + 128];
            float v2 = sm.pv[j + 256]; int i2 = sm.pi[j + 256];
            float v3 = sm.pv[j + 384]; int i3 = sm.pi[j + 384];
            if (v1 > bv) { bv = v1; ix = i1; }
            if (v2 > bv) { bv = v2; ix = i2; }
            if (v3 > bv) { bv = v3; ix = i3; }
            sm.state[j] = bv + xv_cur;
            bp[t * TT + j] = (unsigned char)ix;
            xv_cur = xv_next;
        }
        lds_barrier();
    }

    // ---------------- backward ----------------
    if (tid == 0) {
        // last_tag = argmax(state), first-index tiebreak (sequential strict >)
        float bv = sm.state[0]; int ix = 0;
        for (int i = 1; i < TT; ++i) {
            float v = sm.state[i];
            if (v > bv) { bv = v; ix = i; }
        }
        int carry = ix;
        for (int t = lenb - 1; t >= 1; --t) {
            sm.tags[t] = (unsigned char)carry;
            carry = bp[t * TT + carry];
        }
        sm.tags[0] = (unsigned char)carry;
    }
    lds_barrier();

    int* outb = out + (size_t)b * LL;
    for (int t = tid; t < LL; t += NTH)
        outb[t] = (t < lenb) ? (int)sm.tags[t] : 0;
}

extern "C" void kernel_launch(void* const* d_in, const int* in_sizes, int n_in,
                              void* d_out, int out_size, void* d_ws, size_t ws_size,
                              hipStream_t stream) {
    const float* x       = (const float*)d_in[0];
    const int*   lengths = (const int*)d_in[1];
    // d_in[2] = tags (unused by decode)
    const float* trans   = (const float*)d_in[3];
    int*         out     = (int*)d_out;

    // Backpointers entirely in LDS: 128 KB dynamic + ~5.5 KB static < 160 KB.
    const int dyn = LL * TT;  // 131072 bytes
    hipFuncSetAttribute((const void*)&viterbi_kernel,
                        hipFuncAttributeMaxDynamicSharedMemorySize, dyn);
    viterbi_kernel<<<BB, NTH, dyn, stream>>>(x, lengths, trans, out);
}